// Round 2
// baseline (82.874 us; speedup 1.0000x reference)
//
#include <hip/hip_runtime.h>
#include <hip/hip_bf16.h>
#include <stdint.h>

#define K_DIM 128
#define N_X   8192      // columns of x (the "n" / M dimension)
#define N_WO  8192      // 64*128 flattened (w,o) -> GEMM N dimension
#define OUT_TOTAL (8192UL * 64UL * 128UL)
#define CHUNKS_PER_PANEL 131072   // (8192/16 tiles) * 4 ksteps * 64 lanes

typedef __attribute__((ext_vector_type(8))) short short8;   // 8 bf16 = 4 VGPR
typedef __attribute__((ext_vector_type(4))) float f32x4;

__device__ inline unsigned short f2bf(float f) {
    union { float f; unsigned u; } v; v.f = f;
    unsigned u = v.u;
    u += 0x7fffu + ((u >> 16) & 1u);   // round-to-nearest-even
    return (unsigned short)(u >> 16);
}

// Transpose+convert BOTH panels P[128][8192] f32 (k-major, inner contiguous)
// into MFMA fragment-linear bf16 blocks. Chunk cc = ((t*4 + ks)*64 + l):
//   elem j (0..7): P[ks*32 + (l>>4)*8 + j][t*16 + (l&15)]
// In the GEMM a wave's lane l loads chunk (t,ks,l) and directly has the
// mfma_f32_16x16x32_bf16 A/B fragment for 16-row tile t, K-step ks.
__global__ __launch_bounds__(256) void prep_frag2(const float* __restrict__ X,
                                                  const float* __restrict__ W,
                                                  uint4* __restrict__ Q) {
    int c  = blockIdx.x * 256 + threadIdx.x;   // 0 .. 262143
    int cc = c & (CHUNKS_PER_PANEL - 1);
    const float* P = (c >= CHUNKS_PER_PANEL) ? W : X;
    int l  = cc & 63;
    int ks = (cc >> 6) & 3;
    int t  = cc >> 8;
    int m  = t * 16 + (l & 15);
    int k0 = ks * 32 + ((l >> 4) << 3);
    const float* p = P + (size_t)k0 * N_X + m;
    unsigned short h[8];
#pragma unroll
    for (int j = 0; j < 8; ++j) h[j] = f2bf(p[(size_t)j * N_X]);
    uint4 q;
    q.x = (unsigned)h[0] | ((unsigned)h[1] << 16);
    q.y = (unsigned)h[2] | ((unsigned)h[3] << 16);
    q.z = (unsigned)h[4] | ((unsigned)h[5] << 16);
    q.w = (unsigned)h[6] | ((unsigned)h[7] << 16);
    Q[c] = q;
}

// Fragment-direct GEMM: C[m][n] = sum_k A[m][k]*B[k][n] + 128*bias[n&127].
// A,B pre-laid-out in fragment-linear blocks (see prep_frag2). No LDS.
// Output stores are non-temporal: the 256 MiB write stream must not evict
// the 4 MiB bf16 panels from L2 (panels are re-read by every block).
__global__ __launch_bounds__(256) void gemm_frag(const short8* __restrict__ A,
                                                 const short8* __restrict__ B,
                                                 const float* __restrict__ bias,
                                                 float* __restrict__ out) {
    int bid = blockIdx.x;
    // bijective XCD swizzle (4096 % 8 == 0): consecutive blocks on one XCD
    int swz = (bid & 7) * 512 + (bid >> 3);
    int bm = swz >> 6, bn = swz & 63;

    int tid  = threadIdx.x;
    int lane = tid & 63;
    int w    = tid >> 6;
    int wr = w >> 1, wc = w & 1;
    int m0 = bm * 128 + wr * 64;
    int n0 = bn * 128 + wc * 64;
    int tm0 = m0 >> 4;   // 16-row tile indices
    int tn0 = n0 >> 4;

    f32x4 acc[4][4] = {};
#pragma unroll
    for (int ks = 0; ks < 4; ++ks) {
        short8 a[4], b[4];
#pragma unroll
        for (int i = 0; i < 4; ++i) {
            a[i] = A[((tm0 + i) * 4 + ks) * 64 + lane];
            b[i] = B[((tn0 + i) * 4 + ks) * 64 + lane];
        }
#pragma unroll
        for (int i = 0; i < 4; ++i)
#pragma unroll
            for (int j = 0; j < 4; ++j)
                acc[i][j] = __builtin_amdgcn_mfma_f32_16x16x32_bf16(
                    a[i], b[j], acc[i][j], 0, 0, 0);
    }

    // Epilogue: C/D layout col=lane&15, row=(lane>>4)*4+reg (m89/m91-verified)
    int cl = lane & 15, rg = (lane >> 4) << 2;
#pragma unroll
    for (int j = 0; j < 4; ++j) {
        int ncol = n0 + j * 16 + cl;
        float bv = 128.0f * bias[ncol & 127];
#pragma unroll
        for (int i = 0; i < 4; ++i) {
            int row = m0 + i * 16 + rg;
            float* po = out + (size_t)row * N_WO + ncol;
#pragma unroll
            for (int r = 0; r < 4; ++r)
                __builtin_nontemporal_store(acc[i][j][r] + bv,
                                            po + (size_t)r * N_WO);
        }
    }
}

// Correctness fallback if d_ws is too small for the transposed panels.
__global__ __launch_bounds__(256) void naive_kernel(const float* __restrict__ x,
                                                    const float* __restrict__ wgt,
                                                    const float* __restrict__ bias,
                                                    float* __restrict__ out) {
    size_t idx = (size_t)blockIdx.x * 256 + threadIdx.x;
    if (idx >= OUT_TOTAL) return;
    int n    = (int)(idx >> 13);
    int ncol = (int)(idx & 8191);
    float s = 0.f;
    for (int i = 0; i < K_DIM; ++i)
        s += x[(size_t)i * N_X + n] * wgt[(size_t)i * N_WO + ncol];
    out[idx] = s + 128.0f * bias[ncol & 127];
}

extern "C" void kernel_launch(void* const* d_in, const int* in_sizes, int n_in,
                              void* d_out, int out_size, void* d_ws, size_t ws_size,
                              hipStream_t stream) {
    const float* x    = (const float*)d_in[0];   // [128][8192]
    const float* wgt  = (const float*)d_in[1];   // [128][64*128]
    const float* bias = (const float*)d_in[2];   // [128]
    float* out = (float*)d_out;

    if (ws_size >= 4u * 1024u * 1024u) {
        uint4* wsA = (uint4*)d_ws;                    // 2 MiB: x^T frag bf16
        uint4* wsB = wsA + CHUNKS_PER_PANEL;          // 2 MiB: W   frag bf16
        prep_frag2<<<1024, 256, 0, stream>>>(x, wgt, wsA);
        gemm_frag<<<4096, 256, 0, stream>>>((const short8*)wsA, (const short8*)wsB,
                                            bias, out);
    } else {
        naive_kernel<<<(unsigned)((OUT_TOTAL + 255) / 256), 256, 0, stream>>>(
            x, wgt, bias, out);
    }
}

// Round 3
// 68.708 us; speedup vs baseline: 1.2062x; 1.2062x over previous
//
#include <hip/hip_runtime.h>
#include <hip/hip_bf16.h>
#include <stdint.h>

#define K_DIM 128
#define N_X   8192      // columns of x (the "n" / M dimension)
#define N_WO  8192      // 64*128 flattened (w,o) -> GEMM N dimension
#define OUT_TOTAL (8192UL * 64UL * 128UL)
#define CHUNKS_PER_PANEL 131072   // (8192/16 tiles) * 4 ksteps * 64 lanes

typedef __attribute__((ext_vector_type(8))) short short8;   // 8 bf16 = 4 VGPR
typedef __attribute__((ext_vector_type(4))) float f32x4;

__device__ inline unsigned short f2bf(float f) {
    union { float f; unsigned u; } v; v.f = f;
    unsigned u = v.u;
    u += 0x7fffu + ((u >> 16) & 1u);   // round-to-nearest-even
    return (unsigned short)(u >> 16);
}

// Transpose+convert BOTH panels P[128][8192] f32 (k-major, inner contiguous)
// into MFMA fragment-linear bf16 blocks. Chunk cc = ((t*4 + ks)*64 + l):
//   elem j (0..7): P[ks*32 + (l>>4)*8 + j][t*16 + (l&15)]
// This layout serves as EITHER mfma_16x16x32_bf16 operand:
//   as A-operand: rows = panel m-index; as B-operand: cols = panel m-index.
__global__ __launch_bounds__(256) void prep_frag2(const float* __restrict__ X,
                                                  const float* __restrict__ W,
                                                  uint4* __restrict__ Q) {
    int c  = blockIdx.x * 256 + threadIdx.x;   // 0 .. 262143
    int cc = c & (CHUNKS_PER_PANEL - 1);
    const float* P = (c >= CHUNKS_PER_PANEL) ? W : X;
    int l  = cc & 63;
    int ks = (cc >> 6) & 3;
    int t  = cc >> 8;
    int m  = t * 16 + (l & 15);
    int k0 = ks * 32 + ((l >> 4) << 3);
    const float* p = P + (size_t)k0 * N_X + m;
    unsigned short h[8];
#pragma unroll
    for (int j = 0; j < 8; ++j) h[j] = f2bf(p[(size_t)j * N_X]);
    uint4 q;
    q.x = (unsigned)h[0] | ((unsigned)h[1] << 16);
    q.y = (unsigned)h[2] | ((unsigned)h[3] << 16);
    q.z = (unsigned)h[4] | ((unsigned)h[5] << 16);
    q.w = (unsigned)h[6] | ((unsigned)h[7] << 16);
    Q[c] = q;
}

// Fragment-direct GEMM, no LDS. Operand-SWAPPED mfma:
//   acc[i][j] = mfma(Wfrag_j, xfrag_i, acc)  =>  D[wo][n]
// so each lane's 4 acc regs are 4 CONSECUTIVE wo at one n -> dwordx4 stores.
__global__ __launch_bounds__(256) void gemm_frag(const short8* __restrict__ A,
                                                 const short8* __restrict__ B,
                                                 const float* __restrict__ bias,
                                                 float* __restrict__ out) {
    int bid = blockIdx.x;
    // bijective XCD swizzle (4096 % 8 == 0): consecutive blocks on one XCD
    int swz = (bid & 7) * 512 + (bid >> 3);
    int bm = swz >> 6, bn = swz & 63;

    int tid  = threadIdx.x;
    int lane = tid & 63;
    int w    = tid >> 6;
    int wr = w >> 1, wc = w & 1;
    int m0 = bm * 128 + wr * 64;   // n  (x-column) offset of this wave
    int n0 = bn * 128 + wc * 64;   // wo (flattened w,o) offset of this wave
    int tm0 = m0 >> 4;   // 16-row tile indices
    int tn0 = n0 >> 4;

    f32x4 acc[4][4] = {};
#pragma unroll
    for (int ks = 0; ks < 4; ++ks) {
        short8 a[4], b[4];
#pragma unroll
        for (int i = 0; i < 4; ++i) {
            a[i] = A[((tm0 + i) * 4 + ks) * 64 + lane];
            b[i] = B[((tn0 + i) * 4 + ks) * 64 + lane];
        }
#pragma unroll
        for (int i = 0; i < 4; ++i)
#pragma unroll
            for (int j = 0; j < 4; ++j)
                acc[i][j] = __builtin_amdgcn_mfma_f32_16x16x32_bf16(
                    b[j], a[i], acc[i][j], 0, 0, 0);   // SWAPPED -> D[wo][n]
    }

    // Epilogue: C/D layout col=lane&15 (= n in tile i), row=(lane>>4)*4+reg
    // (= wo in tile j). Lane stores 16B contiguous (4 wo) per fragment.
    int cl = lane & 15, rg = (lane >> 4) << 2;
#pragma unroll
    for (int i = 0; i < 4; ++i) {
        int nrow = m0 + i * 16 + cl;
        float* po_row = out + (size_t)nrow * N_WO;
#pragma unroll
        for (int j = 0; j < 4; ++j) {
            int wo = n0 + j * 16 + rg;         // multiple of 4; o-window safe
            const f32x4 bv = *(const f32x4*)(bias + (wo & 127));
            f32x4 v = acc[i][j];
            v.x = v.x + 128.0f * bv.x;
            v.y = v.y + 128.0f * bv.y;
            v.z = v.z + 128.0f * bv.z;
            v.w = v.w + 128.0f * bv.w;
            *(f32x4*)(po_row + wo) = v;
        }
    }
}

// Correctness fallback if d_ws is too small for the transposed panels.
__global__ __launch_bounds__(256) void naive_kernel(const float* __restrict__ x,
                                                    const float* __restrict__ wgt,
                                                    const float* __restrict__ bias,
                                                    float* __restrict__ out) {
    size_t idx = (size_t)blockIdx.x * 256 + threadIdx.x;
    if (idx >= OUT_TOTAL) return;
    int n    = (int)(idx >> 13);
    int ncol = (int)(idx & 8191);
    float s = 0.f;
    for (int i = 0; i < K_DIM; ++i)
        s += x[(size_t)i * N_X + n] * wgt[(size_t)i * N_WO + ncol];
    out[idx] = s + 128.0f * bias[ncol & 127];
}

extern "C" void kernel_launch(void* const* d_in, const int* in_sizes, int n_in,
                              void* d_out, int out_size, void* d_ws, size_t ws_size,
                              hipStream_t stream) {
    const float* x    = (const float*)d_in[0];   // [128][8192]
    const float* wgt  = (const float*)d_in[1];   // [128][64*128]
    const float* bias = (const float*)d_in[2];   // [128]
    float* out = (float*)d_out;

    if (ws_size >= 4u * 1024u * 1024u) {
        uint4* wsA = (uint4*)d_ws;                    // 2 MiB: x^T frag bf16
        uint4* wsB = wsA + CHUNKS_PER_PANEL;          // 2 MiB: W   frag bf16
        prep_frag2<<<1024, 256, 0, stream>>>(x, wgt, wsA);
        gemm_frag<<<4096, 256, 0, stream>>>((const short8*)wsA, (const short8*)wsB,
                                            bias, out);
    } else {
        naive_kernel<<<(unsigned)((OUT_TOTAL + 255) / 256), 256, 0, stream>>>(
            x, wgt, bias, out);
    }
}

// Round 4
// 67.193 us; speedup vs baseline: 1.2334x; 1.0225x over previous
//
#include <hip/hip_runtime.h>
#include <hip/hip_bf16.h>
#include <stdint.h>

#define K_DIM 128
#define N_X   8192      // columns of x (the "n" / M dimension)
#define N_WO  8192      // 64*128 flattened (w,o) -> GEMM N dimension
#define OUT_TOTAL (8192UL * 64UL * 128UL)
#define CHUNKS_PER_PANEL 131072   // (8192/16 tiles) * 4 ksteps * 64 lanes

typedef __attribute__((ext_vector_type(8))) short short8;   // 8 bf16 = 4 VGPR
typedef __attribute__((ext_vector_type(4))) float f32x4;

__device__ inline unsigned short f2bf(float f) {
    union { float f; unsigned u; } v; v.f = f;
    unsigned u = v.u;
    u += 0x7fffu + ((u >> 16) & 1u);   // round-to-nearest-even
    return (unsigned short)(u >> 16);
}

// Transpose+convert BOTH panels P[128][8192] f32 (k-major, inner contiguous)
// into MFMA fragment-linear bf16 blocks. Chunk cc = ((t*4 + ks)*64 + l):
//   elem j (0..7): P[ks*32 + (l>>4)*8 + j][t*16 + (l&15)]
__global__ __launch_bounds__(256) void prep_frag2(const float* __restrict__ X,
                                                  const float* __restrict__ W,
                                                  uint4* __restrict__ Q) {
    int c  = blockIdx.x * 256 + threadIdx.x;   // 0 .. 262143
    int cc = c & (CHUNKS_PER_PANEL - 1);
    const float* P = (c >= CHUNKS_PER_PANEL) ? W : X;
    int l  = cc & 63;
    int ks = (cc >> 6) & 3;
    int t  = cc >> 8;
    int m  = t * 16 + (l & 15);
    int k0 = ks * 32 + ((l >> 4) << 3);
    const float* p = P + (size_t)k0 * N_X + m;
    unsigned short h[8];
#pragma unroll
    for (int j = 0; j < 8; ++j) h[j] = f2bf(p[(size_t)j * N_X]);
    uint4 q;
    q.x = (unsigned)h[0] | ((unsigned)h[1] << 16);
    q.y = (unsigned)h[2] | ((unsigned)h[3] << 16);
    q.z = (unsigned)h[4] | ((unsigned)h[5] << 16);
    q.w = (unsigned)h[6] | ((unsigned)h[7] << 16);
    Q[c] = q;
}

// 256x256-tile GEMM, panels LDS-staged once per block (fragment-linear, so
// each block slice is a CONTIGUOUS 64 KiB range -> linear global_load_lds).
// 8 waves of 128n x 64wo. Operand-SWAPPED mfma: acc = mfma(Wfrag, xfrag)
// => D[wo][n]; lane holds 4 consecutive wo at one n -> dwordx4 stores.
__global__ __launch_bounds__(512, 2) void gemm_lds(const uint4* __restrict__ A,
                                                   const uint4* __restrict__ B,
                                                   const float* __restrict__ bias,
                                                   float* __restrict__ out) {
    extern __shared__ uint4 lds[];      // 8192 chunks: A 4096 | B 4096
    uint4* ldsA = lds;
    uint4* ldsB = lds + 4096;

    int bid = blockIdx.x;
    // bijective XCD swizzle (1024 % 8 == 0)
    int swz = (bid & 7) * 128 + (bid >> 3);
    int bm = swz >> 5, bn = swz & 31;

    int tid  = threadIdx.x;
    int lane = tid & 63;
    int w    = tid >> 6;               // 0..7
    int wr = w >> 2;                   // 0..1 : n-direction (128 rows each)
    int wc = w & 3;                    // 0..3 : wo-direction (64 cols each)

    // ---- stage both 64 KiB slices into LDS (16 x 1KiB wave-issues each) ----
    const uint4* gA = A + bm * 4096;
    const uint4* gB = B + bn * 4096;
#pragma unroll
    for (int q = 0; q < 8; ++q) {
        int c = (q * 8 + w) * 64;      // wave-uniform chunk base
        __builtin_amdgcn_global_load_lds(
            (const __attribute__((address_space(1))) void*)(gA + c + lane),
            (__attribute__((address_space(3))) void*)(ldsA + c), 16, 0, 0);
        __builtin_amdgcn_global_load_lds(
            (const __attribute__((address_space(1))) void*)(gB + c + lane),
            (__attribute__((address_space(3))) void*)(ldsB + c), 16, 0, 0);
    }
    __syncthreads();

    // ---- MFMA: 8x4 fragments per wave, K=128 in 4 steps ----
    const short8* fA = (const short8*)ldsA;
    const short8* fB = (const short8*)ldsB;
    f32x4 acc[8][4] = {};
#pragma unroll
    for (int ks = 0; ks < 4; ++ks) {
        short8 a[8], b[4];
#pragma unroll
        for (int i = 0; i < 8; ++i)
            a[i] = fA[((wr * 8 + i) * 4 + ks) * 64 + lane];
#pragma unroll
        for (int j = 0; j < 4; ++j)
            b[j] = fB[((wc * 4 + j) * 4 + ks) * 64 + lane];
#pragma unroll
        for (int i = 0; i < 8; ++i)
#pragma unroll
            for (int j = 0; j < 4; ++j)
                acc[i][j] = __builtin_amdgcn_mfma_f32_16x16x32_bf16(
                    b[j], a[i], acc[i][j], 0, 0, 0);   // SWAPPED -> D[wo][n]
    }

    // ---- epilogue: col(lane&15)=n, row((lane>>4)*4+reg)=wo ----
    int m0 = bm * 256 + wr * 128;
    int n0 = bn * 256 + wc * 64;
    int cl = lane & 15, rg = (lane >> 4) << 2;
#pragma unroll
    for (int i = 0; i < 8; ++i) {
        int nrow = m0 + i * 16 + cl;
        float* po_row = out + (size_t)nrow * N_WO;
#pragma unroll
        for (int j = 0; j < 4; ++j) {
            int wo = n0 + j * 16 + rg;              // multiple of 4
            const f32x4 bv = *(const f32x4*)(bias + (wo & 127));
            f32x4 v = acc[i][j];
            v.x = v.x + 128.0f * bv.x;
            v.y = v.y + 128.0f * bv.y;
            v.z = v.z + 128.0f * bv.z;
            v.w = v.w + 128.0f * bv.w;
            *(f32x4*)(po_row + wo) = v;
        }
    }
}

// Correctness fallback if d_ws is too small for the transposed panels.
__global__ __launch_bounds__(256) void naive_kernel(const float* __restrict__ x,
                                                    const float* __restrict__ wgt,
                                                    const float* __restrict__ bias,
                                                    float* __restrict__ out) {
    size_t idx = (size_t)blockIdx.x * 256 + threadIdx.x;
    if (idx >= OUT_TOTAL) return;
    int n    = (int)(idx >> 13);
    int ncol = (int)(idx & 8191);
    float s = 0.f;
    for (int i = 0; i < K_DIM; ++i)
        s += x[(size_t)i * N_X + n] * wgt[(size_t)i * N_WO + ncol];
    out[idx] = s + 128.0f * bias[ncol & 127];
}

extern "C" void kernel_launch(void* const* d_in, const int* in_sizes, int n_in,
                              void* d_out, int out_size, void* d_ws, size_t ws_size,
                              hipStream_t stream) {
    const float* x    = (const float*)d_in[0];   // [128][8192]
    const float* wgt  = (const float*)d_in[1];   // [128][64*128]
    const float* bias = (const float*)d_in[2];   // [128]
    float* out = (float*)d_out;

    if (ws_size >= 4u * 1024u * 1024u) {
        uint4* wsA = (uint4*)d_ws;                    // 2 MiB: x^T frag bf16
        uint4* wsB = wsA + CHUNKS_PER_PANEL;          // 2 MiB: W   frag bf16
        prep_frag2<<<1024, 256, 0, stream>>>(x, wgt, wsA);
        gemm_lds<<<1024, 512, 131072, stream>>>((const uint4*)wsA, (const uint4*)wsB,
                                                bias, out);
    } else {
        naive_kernel<<<(unsigned)((OUT_TOTAL + 255) / 256), 256, 0, stream>>>(
            x, wgt, bias, out);
    }
}

// Round 5
// 65.165 us; speedup vs baseline: 1.2718x; 1.0311x over previous
//
#include <hip/hip_runtime.h>
#include <hip/hip_bf16.h>
#include <stdint.h>

#define K_DIM 128
#define N_X   8192      // columns of x (the "n" / M dimension)
#define N_WO  8192      // 64*128 flattened (w,o) -> GEMM N dimension
#define OUT_TOTAL (8192UL * 64UL * 128UL)
#define CHUNKS_PER_PANEL 131072   // (8192/16 tiles) * 4 ksteps * 64 lanes

typedef __attribute__((ext_vector_type(8))) short short8;   // 8 bf16 = 4 VGPR
typedef __attribute__((ext_vector_type(4))) float f32x4;

__device__ inline unsigned short f2bf(float f) {
    union { float f; unsigned u; } v; v.f = f;
    unsigned u = v.u;
    u += 0x7fffu + ((u >> 16) & 1u);   // round-to-nearest-even
    return (unsigned short)(u >> 16);
}

// Transpose+convert BOTH panels P[128][8192] f32 (k-major, inner contiguous)
// into MFMA fragment-linear bf16 blocks. Chunk cc = ((t*4 + ks)*64 + l):
//   elem j (0..7): P[ks*32 + (l>>4)*8 + j][t*16 + (l&15)]
__global__ __launch_bounds__(256) void prep_frag2(const float* __restrict__ X,
                                                  const float* __restrict__ W,
                                                  uint4* __restrict__ Q) {
    int c  = blockIdx.x * 256 + threadIdx.x;   // 0 .. 262143
    int cc = c & (CHUNKS_PER_PANEL - 1);
    const float* P = (c >= CHUNKS_PER_PANEL) ? W : X;
    int l  = cc & 63;
    int ks = (cc >> 6) & 3;
    int t  = cc >> 8;
    int m  = t * 16 + (l & 15);
    int k0 = ks * 32 + ((l >> 4) << 3);
    const float* p = P + (size_t)k0 * N_X + m;
    unsigned short h[8];
#pragma unroll
    for (int j = 0; j < 8; ++j) h[j] = f2bf(p[(size_t)j * N_X]);
    uint4 q;
    q.x = (unsigned)h[0] | ((unsigned)h[1] << 16);
    q.y = (unsigned)h[2] | ((unsigned)h[3] << 16);
    q.z = (unsigned)h[4] | ((unsigned)h[5] << 16);
    q.w = (unsigned)h[6] | ((unsigned)h[7] << 16);
    Q[c] = q;
}

// Row-slab sweep GEMM: block = 32 output rows (n) x ALL 8192 wo.
// Output region out[n0:n0+32][*] is CONTIGUOUS 1 MiB, swept monotonically in
// 16 iterations -> stores flow continuously (no phases, no barriers, no LDS),
// and each CU keeps only 32 linear HBM write streams (page-friendly).
// x-frags (8 KiB) stay in registers for the whole kernel; W-frags stream from
// L2 (panel is 2 MiB, L2-resident per XCD). Operand-SWAPPED mfma:
//   acc = mfma(Wfrag, xfrag) => D[wo][n]; lane = 4 consecutive wo at one n.
__global__ __launch_bounds__(512, 2) void gemm_sweep(const short8* __restrict__ A,
                                                     const short8* __restrict__ B,
                                                     const float* __restrict__ bias,
                                                     float* __restrict__ out) {
    int bid = blockIdx.x;
    // bijective XCD swizzle (256 % 8 == 0): 32 consecutive slabs per XCD
    int swz = (bid & 7) * 32 + (bid >> 3);
    int n0  = swz * 32;

    int tid  = threadIdx.x;
    int lane = tid & 63;
    int w    = tid >> 6;               // 0..7

    // x fragments for this block's 2 row-tiles, all 4 K-steps (held in VGPRs)
    int tA = swz * 2;
    short8 xf[2][4];
#pragma unroll
    for (int i = 0; i < 2; ++i)
#pragma unroll
        for (int ks = 0; ks < 4; ++ks)
            xf[i][ks] = A[((tA + i) * 4 + ks) * 64 + lane];

    int cl = lane & 15, rg = (lane >> 4) << 2;

    // bias: (tj*16+rg) mod 128 is iteration-invariant per (w,j) since
    // it*32 % 8 == 0 -> hoist 4 premultiplied float4s into registers.
    f32x4 bvs[4];
#pragma unroll
    for (int j = 0; j < 4; ++j) {
        const f32x4 bv = *(const f32x4*)(bias + ((((w * 4 + j) & 7) << 4) + rg));
        bvs[j].x = 128.0f * bv.x;  bvs[j].y = 128.0f * bv.y;
        bvs[j].z = 128.0f * bv.z;  bvs[j].w = 128.0f * bv.w;
    }

    float* out0 = out + (size_t)n0 * N_WO;
    float* out1 = out0 + 16 * N_WO;

#pragma unroll 2
    for (int it = 0; it < 16; ++it) {
        int tj0 = it * 32 + w * 4;     // this wave's 4 wo-tiles this iteration
        short8 wf[4][4];
#pragma unroll
        for (int j = 0; j < 4; ++j)
#pragma unroll
            for (int ks = 0; ks < 4; ++ks)
                wf[j][ks] = B[((tj0 + j) * 4 + ks) * 64 + lane];

        f32x4 acc[2][4] = {};
#pragma unroll
        for (int ks = 0; ks < 4; ++ks)
#pragma unroll
            for (int i = 0; i < 2; ++i)
#pragma unroll
                for (int j = 0; j < 4; ++j)
                    acc[i][j] = __builtin_amdgcn_mfma_f32_16x16x32_bf16(
                        wf[j][ks], xf[i][ks], acc[i][j], 0, 0, 0); // D[wo][n]

        // stores: col(lane&15)=n within tile i, row((lane>>4)*4+reg)=wo
        float* po0 = out0 + (size_t)cl * N_WO;
        float* po1 = out1 + (size_t)cl * N_WO;
#pragma unroll
        for (int j = 0; j < 4; ++j) {
            int wo = (tj0 + j) * 16 + rg;
            f32x4 v0 = acc[0][j], v1 = acc[1][j];
            v0.x += bvs[j].x; v0.y += bvs[j].y; v0.z += bvs[j].z; v0.w += bvs[j].w;
            v1.x += bvs[j].x; v1.y += bvs[j].y; v1.z += bvs[j].z; v1.w += bvs[j].w;
            *(f32x4*)(po0 + wo) = v0;
            *(f32x4*)(po1 + wo) = v1;
        }
    }
}

// Correctness fallback if d_ws is too small for the transposed panels.
__global__ __launch_bounds__(256) void naive_kernel(const float* __restrict__ x,
                                                    const float* __restrict__ wgt,
                                                    const float* __restrict__ bias,
                                                    float* __restrict__ out) {
    size_t idx = (size_t)blockIdx.x * 256 + threadIdx.x;
    if (idx >= OUT_TOTAL) return;
    int n    = (int)(idx >> 13);
    int ncol = (int)(idx & 8191);
    float s = 0.f;
    for (int i = 0; i < K_DIM; ++i)
        s += x[(size_t)i * N_X + n] * wgt[(size_t)i * N_WO + ncol];
    out[idx] = s + 128.0f * bias[ncol & 127];
}

extern "C" void kernel_launch(void* const* d_in, const int* in_sizes, int n_in,
                              void* d_out, int out_size, void* d_ws, size_t ws_size,
                              hipStream_t stream) {
    const float* x    = (const float*)d_in[0];   // [128][8192]
    const float* wgt  = (const float*)d_in[1];   // [128][64*128]
    const float* bias = (const float*)d_in[2];   // [128]
    float* out = (float*)d_out;

    if (ws_size >= 4u * 1024u * 1024u) {
        uint4* wsA = (uint4*)d_ws;                    // 2 MiB: x^T frag bf16
        uint4* wsB = wsA + CHUNKS_PER_PANEL;          // 2 MiB: W   frag bf16
        prep_frag2<<<1024, 256, 0, stream>>>(x, wgt, wsA);
        gemm_sweep<<<256, 512, 0, stream>>>((const short8*)wsA, (const short8*)wsB,
                                            bias, out);
    } else {
        naive_kernel<<<(unsigned)((OUT_TOTAL + 255) / 256), 256, 0, stream>>>(
            x, wgt, bias, out);
    }
}